// Round 5
// baseline (239.155 us; speedup 1.0000x reference)
//
#include <hip/hip_runtime.h>

#define N_NODES 100000
#define N_EDGES 1600000
#define EPS 1e-5f

#define NWB   25000   // waves in gather_kernel
#define NBLKB 6250    // gather blocks (4 waves each); 4 nodes per wave

typedef __bf16 bf16x8 __attribute__((ext_vector_type(8)));
typedef float  f32x4  __attribute__((ext_vector_type(4)));

__device__ __forceinline__ unsigned short f2bf(float f) {
  return __builtin_bit_cast(unsigned short, static_cast<__bf16>(f));
}

// ---------------------------------------------------------------------------
// Algebraic decomposition: h[e] = W@[feat[dst]; node[dst]-node[src]]
//   = g[dst] - b[src],   g[v] = W@[feat[v]; node[v]],  b[v] = Wn@node[v].
// GEMM is per-NODE (16x less work than per-edge); hot pass is a pure gather.
// ---------------------------------------------------------------------------

// Kernel 0: W (64x67 f32) -> bf16 padded 64x96.
__global__ __launch_bounds__(256) void prepw_kernel(
    const float* __restrict__ W, unsigned short* __restrict__ Wbf) {
  int wi = blockIdx.x * 256 + threadIdx.x;   // < 6144 = 64*96
  int n = wi / 96, c = wi % 96;
  Wbf[wi] = (c < 67) ? f2bf(W[n * 67 + c]) : (unsigned short)0;
}

// Kernel 1: dense g-table GEMM. Wave w computes rows 16w..16w+15 of
// g = [feat|node] @ W^T, stores bf16. MFMA 16x16x32 bf16 layouts (verified):
//   A[m=lane&15][k=quad*8+j], B[k=quad*8+j][n=lane&15], D col=lane&15,
//   row=quad*4+reg.
__global__ __launch_bounds__(256) void gtable_kernel(
    const float* __restrict__ feat, const float* __restrict__ nodep,
    const unsigned short* __restrict__ Wbf, unsigned short* __restrict__ gtab) {
  const int lane = threadIdx.x & 63;
  const int wave = (int)((blockIdx.x * blockDim.x + threadIdx.x) >> 6);
  if (wave >= 6250) return;
  const int c = lane & 15, quad = lane >> 4;
  const int row0 = wave * 16;

  bf16x8 Bfrag[4][3];
#pragma unroll
  for (int t = 0; t < 4; ++t) {
    const unsigned short* wrow = Wbf + (t * 16 + c) * 96 + quad * 8;
#pragma unroll
    for (int s = 0; s < 3; ++s)
      Bfrag[t][s] = *(const bf16x8*)(wrow + s * 32);
  }

  // A fragments from f32 features (convert on the fly)
  const float* fr = feat + (size_t)(row0 + c) * 64 + quad * 8;
  f32x4 fa = *(const f32x4*)(fr);
  f32x4 fb = *(const f32x4*)(fr + 4);
  f32x4 fc = *(const f32x4*)(fr + 32);
  f32x4 fd = *(const f32x4*)(fr + 36);
  bf16x8 A0, A1;
#pragma unroll
  for (int j = 0; j < 4; ++j) {
    A0[j] = (__bf16)fa[j]; A0[4 + j] = (__bf16)fb[j];
    A1[j] = (__bf16)fc[j]; A1[4 + j] = (__bf16)fd[j];
  }
  bf16x8 A2;
#pragma unroll
  for (int j = 0; j < 8; ++j) A2[j] = (__bf16)0.0f;
  if (quad == 0) {
    const float* np = nodep + (size_t)(row0 + c) * 3;
    A2[0] = (__bf16)np[0]; A2[1] = (__bf16)np[1]; A2[2] = (__bf16)np[2];
  }

#pragma unroll
  for (int t = 0; t < 4; ++t) {
    f32x4 acc = {0.f, 0.f, 0.f, 0.f};
    acc = __builtin_amdgcn_mfma_f32_16x16x32_bf16(A0, Bfrag[t][0], acc, 0, 0, 0);
    acc = __builtin_amdgcn_mfma_f32_16x16x32_bf16(A1, Bfrag[t][1], acc, 0, 0, 0);
    acc = __builtin_amdgcn_mfma_f32_16x16x32_bf16(A2, Bfrag[t][2], acc, 0, 0, 0);
#pragma unroll
    for (int r = 0; r < 4; ++r)
      gtab[(size_t)(row0 + quad * 4 + r) * 64 + t * 16 + c] = f2bf(acc[r]);
  }
}

// Kernel 2: gather pass. Wave handles 4 nodes (i = wave + j*NWB); lane = column.
//  - 64 edge-dst indices in one load (node j, edge k at lane j*16+k)
//  - per node: 16 INDEPENDENT coalesced 128B row loads from gtab (deep MLP)
//  - signed max (gamma-sign trick), sum S, sumsq Q; b recomputed from node
//  - writes sel - b to d_out; 5 block-partials -> stats[320][NBLKB]
// No MFMA, no Bfrag: VGPR stays under 64 -> 8 waves/SIMD.
__global__ __launch_bounds__(256) void gather_kernel(
    const float* __restrict__ nodep, const float* __restrict__ W,
    const float* __restrict__ gamma, const int* __restrict__ edges,
    const unsigned short* __restrict__ gtab,
    float* __restrict__ out, float* __restrict__ stats) {
  const int lane = threadIdx.x & 63;
  const int wave = (int)((blockIdx.x * blockDim.x + threadIdx.x) >> 6);

  const float wn0 = W[lane * 67 + 64];
  const float wn1 = W[lane * 67 + 65];
  const float wn2 = W[lane * 67 + 66];
  const float gs  = (gamma[lane] >= 0.f) ? 1.f : -1.f;

  int dst_all = edges[2 * (wave + (lane >> 4) * NWB + (lane & 15) * N_NODES) + 1];

  float P1 = 0.f, P2 = 0.f, P3 = 0.f, P4 = 0.f, P5 = 0.f;

#pragma unroll
  for (int j = 0; j < 4; ++j) {
    const int i = wave + j * NWB;
    int dk[16];
#pragma unroll
    for (int k = 0; k < 16; ++k) dk[k] = __shfl(dst_all, j * 16 + k, 64);
    float v[16];
#pragma unroll
    for (int k = 0; k < 16; ++k) {
      unsigned int u = (unsigned int)gtab[(size_t)dk[k] * 64 + lane];
      v[k] = __builtin_bit_cast(float, u << 16);
    }
    float S = 0.f, Q = 0.f, M = -1e30f;
#pragma unroll
    for (int k = 0; k < 16; ++k) {
      S += v[k];
      Q = fmaf(v[k], v[k], Q);
      M = fmaxf(M, gs * v[k]);
    }
    float nx = nodep[3 * i], ny = nodep[3 * i + 1], nz = nodep[3 * i + 2];
    float b = wn0 * nx + wn1 * ny + wn2 * nz;
    out[(size_t)i * 64 + lane] = gs * M - b;   // h of the selected (max) edge
    P1 += S; P2 += Q; P3 = fmaf(b, S, P3); P4 += b; P5 = fmaf(b, b, P5);
  }

  // block reduce of 5 column-partials
  __shared__ float red[4][5][64];
  const int wv = threadIdx.x >> 6;
  red[wv][0][lane] = P1; red[wv][1][lane] = P2; red[wv][2][lane] = P3;
  red[wv][3][lane] = P4; red[wv][4][lane] = P5;
  __syncthreads();
  for (int idx = threadIdx.x; idx < 320; idx += 256) {
    int p = idx >> 6, d = idx & 63;
    float s = (red[0][p][d] + red[1][p][d]) + (red[2][p][d] + red[3][p][d]);
    stats[(size_t)idx * NBLKB + blockIdx.x] = s;
  }
}

// Kernel 3: reduce partials -> scale/shift per column.
//   sum_h  = P1 - 16*P4;  sum_h2 = P2 - 2*P3 + 16*P5
__global__ __launch_bounds__(256) void stats_kernel(
    const float* __restrict__ stats, const float* __restrict__ gamma,
    const float* __restrict__ beta, float* __restrict__ ss) {
  const int d = blockIdx.x, t = threadIdx.x;
  float a[5];
#pragma unroll
  for (int p = 0; p < 5; ++p) {
    const float* r = stats + (size_t)(p * 64 + d) * NBLKB;
    float s = 0.f;
    for (int k = t; k < NBLKB; k += 256) s += r[k];
    a[p] = s;
  }
  __shared__ float l[5][256];
#pragma unroll
  for (int p = 0; p < 5; ++p) l[p][t] = a[p];
  __syncthreads();
  for (int s = 128; s > 0; s >>= 1) {
    if (t < s) {
#pragma unroll
      for (int p = 0; p < 5; ++p) l[p][t] += l[p][t + s];
    }
    __syncthreads();
  }
  if (t == 0) {
    float P1 = l[0][0], P2 = l[1][0], P3 = l[2][0], P4 = l[3][0], P5 = l[4][0];
    const float inv = 1.0f / (float)N_EDGES;
    float mean = (P1 - 16.f * P4) * inv;
    float eh2  = (P2 - 2.f * P3 + 16.f * P5) * inv;
    float var  = fmaxf(eh2 - mean * mean, 0.f);
    float sc   = gamma[d] * rsqrtf(var + EPS);
    ss[d]      = sc;
    ss[64 + d] = beta[d] - mean * sc;
  }
}

// Kernel 4: out = relu(out*scale + shift), in place. sel already encodes the
// max/min choice; result >= 0 also covers the reference's zeros-init .at[].max.
__global__ __launch_bounds__(256) void finalize_kernel(
    const float* __restrict__ ss, float* out) {
  int idx = blockIdx.x * 256 + threadIdx.x;   // < 6,400,000
  int d = idx & 63;
  out[idx] = fmaxf(fmaf(out[idx], ss[d], ss[64 + d]), 0.f);
}

// ---------------------------------------------------------------------------
extern "C" void kernel_launch(void* const* d_in, const int* in_sizes, int n_in,
                              void* d_out, int out_size, void* d_ws, size_t ws_size,
                              hipStream_t stream) {
  const float* nodep = (const float*)d_in[0];
  const float* feat  = (const float*)d_in[1];
  const float* W     = (const float*)d_in[2];
  const float* gamma = (const float*)d_in[3];
  const float* beta  = (const float*)d_in[4];
  const int*   edges = (const int*)d_in[5];

  // workspace layout (16B-aligned); total ~20.8 MB
  char* ws = (char*)d_ws;
  unsigned short* Wbf  = (unsigned short*)ws;                    //    12,288 B
  unsigned short* gtab = (unsigned short*)(ws + 12288);          // 12,800,000 B
  float* stats = (float*)(ws + 12288 + 12800000);                //  8,000,000 B (320*6250*4)
  float* ss    = (float*)(ws + 12288 + 12800000 + 8000000);      //       512 B
  float* outp  = (float*)d_out;

  prepw_kernel<<<24, 256, 0, stream>>>(W, Wbf);
  gtable_kernel<<<1563, 256, 0, stream>>>(feat, nodep, Wbf, gtab);
  gather_kernel<<<NBLKB, 256, 0, stream>>>(nodep, W, gamma, edges, gtab,
                                           outp, stats);
  stats_kernel<<<64, 256, 0, stream>>>(stats, gamma, beta, ss);
  finalize_kernel<<<25000, 256, 0, stream>>>(ss, outp);
}

// Round 6
// 198.288 us; speedup vs baseline: 1.2061x; 1.2061x over previous
//
#include <hip/hip_runtime.h>

#define N_NODES 100000
#define N_EDGES 1600000
#define EPS 1e-5f

#define NWB   25000   // waves in gather_kernel
#define NBLKB 6250    // gather blocks (4 waves each); 4 nodes per wave

typedef __bf16 bf16x8 __attribute__((ext_vector_type(8)));
typedef float  f32x4  __attribute__((ext_vector_type(4)));

__device__ __forceinline__ unsigned short f2bf(float f) {
  return __builtin_bit_cast(unsigned short, static_cast<__bf16>(f));
}

// ---------------------------------------------------------------------------
// Algebraic decomposition: h[e] = W@[feat[dst]; node[dst]-node[src]]
//   = g[dst] - b[src],   g[v] = W@[feat[v]; node[v]],  b[v] = Wn@node[v].
// GEMM is per-NODE (16x less work); hot pass is a vector gather-reduce.
// ---------------------------------------------------------------------------

// Kernel 0: W (64x67 f32) -> bf16 padded 64x96.
__global__ __launch_bounds__(256) void prepw_kernel(
    const float* __restrict__ W, unsigned short* __restrict__ Wbf) {
  int wi = blockIdx.x * 256 + threadIdx.x;   // < 6144 = 64*96
  int n = wi / 96, c = wi % 96;
  Wbf[wi] = (c < 67) ? f2bf(W[n * 67 + c]) : (unsigned short)0;
}

// Kernel 1: dense g-table GEMM (100k x 67 @ 67 x 64), bf16 out.
// MFMA 16x16x32 bf16 layouts (HW-verified): A[m=lane&15][k=quad*8+j],
// B[k=quad*8+j][n=lane&15], D col=lane&15, row=quad*4+reg.
__global__ __launch_bounds__(256) void gtable_kernel(
    const float* __restrict__ feat, const float* __restrict__ nodep,
    const unsigned short* __restrict__ Wbf, unsigned short* __restrict__ gtab) {
  const int lane = threadIdx.x & 63;
  const int wave = (int)((blockIdx.x * blockDim.x + threadIdx.x) >> 6);
  if (wave >= 6250) return;
  const int c = lane & 15, quad = lane >> 4;
  const int row0 = wave * 16;

  bf16x8 Bfrag[4][3];
#pragma unroll
  for (int t = 0; t < 4; ++t) {
    const unsigned short* wrow = Wbf + (t * 16 + c) * 96 + quad * 8;
#pragma unroll
    for (int s = 0; s < 3; ++s)
      Bfrag[t][s] = *(const bf16x8*)(wrow + s * 32);
  }

  const float* fr = feat + (size_t)(row0 + c) * 64 + quad * 8;
  f32x4 fa = *(const f32x4*)(fr);
  f32x4 fb = *(const f32x4*)(fr + 4);
  f32x4 fc = *(const f32x4*)(fr + 32);
  f32x4 fd = *(const f32x4*)(fr + 36);
  bf16x8 A0, A1;
#pragma unroll
  for (int j = 0; j < 4; ++j) {
    A0[j] = (__bf16)fa[j]; A0[4 + j] = (__bf16)fb[j];
    A1[j] = (__bf16)fc[j]; A1[4 + j] = (__bf16)fd[j];
  }
  bf16x8 A2;
#pragma unroll
  for (int j = 0; j < 8; ++j) A2[j] = (__bf16)0.0f;
  if (quad == 0) {
    const float* np = nodep + (size_t)(row0 + c) * 3;
    A2[0] = (__bf16)np[0]; A2[1] = (__bf16)np[1]; A2[2] = (__bf16)np[2];
  }

#pragma unroll
  for (int t = 0; t < 4; ++t) {
    f32x4 acc = {0.f, 0.f, 0.f, 0.f};
    acc = __builtin_amdgcn_mfma_f32_16x16x32_bf16(A0, Bfrag[t][0], acc, 0, 0, 0);
    acc = __builtin_amdgcn_mfma_f32_16x16x32_bf16(A1, Bfrag[t][1], acc, 0, 0, 0);
    acc = __builtin_amdgcn_mfma_f32_16x16x32_bf16(A2, Bfrag[t][2], acc, 0, 0, 0);
#pragma unroll
    for (int r = 0; r < 4; ++r)
      gtab[(size_t)(row0 + quad * 4 + r) * 64 + t * 16 + c] = f2bf(acc[r]);
  }
}

// Kernel 2: gather pass, vector loads via LDS transpose. Wave = 4 nodes.
// Per node: 2 b128 global loads/lane stage 16 g-rows (lane = row(l>>3) x
// 16B-chunk(l&7)) into per-wave LDS; 16 ds_read_u16/lane recover column
// ownership (row stride 128 B, lane*2 within row: conflict-free).
// Double-buffered: node j+1's global loads issue BEFORE node j's reduce;
// its ds_writes go after. R5 post-mortem: scalar u16 gathers got serialized
// by the register allocator (VGPR=28, ~1 load in flight); b128 can't be split.
__global__ __launch_bounds__(256) void gather_kernel(
    const float* __restrict__ nodep, const float* __restrict__ W,
    const float* __restrict__ gamma, const int* __restrict__ edges,
    const unsigned short* __restrict__ gtab,
    float* __restrict__ out, float* __restrict__ stats) {
  const int lane = threadIdx.x & 63;
  const int wv   = threadIdx.x >> 6;            // wave in block
  const int wave = blockIdx.x * 4 + wv;

  // 16 KB staging: [wave][buf][row*64+col] (ushort); reused for reduction.
  __shared__ __align__(16) unsigned short smem[4][2][16 * 64];

  const float wn0 = W[lane * 67 + 64];
  const float wn1 = W[lane * 67 + 65];
  const float wn2 = W[lane * 67 + 66];
  const float gs  = (gamma[lane] >= 0.f) ? 1.f : -1.f;

  int dst_all = edges[2 * (wave + (lane >> 4) * NWB + (lane & 15) * N_NODES) + 1];

  const int rg = lane >> 3;    // row within 8-row group
  const int ch = lane & 7;     // 16-byte chunk within row

  float P1 = 0.f, P2 = 0.f, P3 = 0.f, P4 = 0.f, P5 = 0.f;

  // stage node j's 16 rows -> registers (2 b128 loads)
  bf16x8 g0, g1;
  auto stage_load = [&](int j) {
    int d0 = __shfl(dst_all, j * 16 + rg, 64);
    int d1 = __shfl(dst_all, j * 16 + 8 + rg, 64);
    g0 = *(const bf16x8*)(gtab + (size_t)d0 * 64 + ch * 8);
    g1 = *(const bf16x8*)(gtab + (size_t)d1 * 64 + ch * 8);
  };
  auto stage_write = [&](int buf) {
    *(bf16x8*)&smem[wv][buf][rg * 64 + ch * 8]       = g0;
    *(bf16x8*)&smem[wv][buf][(8 + rg) * 64 + ch * 8] = g1;
  };

  stage_load(0);
  stage_write(0);

#pragma unroll
  for (int j = 0; j < 4; ++j) {
    const int buf = j & 1;
    if (j < 3) stage_load(j + 1);          // global latency overlaps reduce

    float S = 0.f, Q = 0.f, M = -1e30f;
#pragma unroll
    for (int k = 0; k < 16; ++k) {
      unsigned int u = (unsigned int)smem[wv][buf][k * 64 + lane];
      float v = __builtin_bit_cast(float, u << 16);
      S += v;
      Q = fmaf(v, v, Q);
      M = fmaxf(M, gs * v);
    }
    const int i = wave + j * NWB;
    float nx = nodep[3 * i], ny = nodep[3 * i + 1], nz = nodep[3 * i + 2];
    float b = wn0 * nx + wn1 * ny + wn2 * nz;
    out[(size_t)i * 64 + lane] = gs * M - b;   // signed-max edge value minus b
    P1 += S; P2 += Q; P3 = fmaf(b, S, P3); P4 += b; P5 = fmaf(b, b, P5);

    if (j < 3) stage_write(buf ^ 1);
  }

  // block reduce of the 5 column-partials; overlay red onto smem
  __syncthreads();                            // staging reads all done
  float* red = (float*)smem;                  // [4][5][64]
  red[(wv * 5 + 0) * 64 + lane] = P1;
  red[(wv * 5 + 1) * 64 + lane] = P2;
  red[(wv * 5 + 2) * 64 + lane] = P3;
  red[(wv * 5 + 3) * 64 + lane] = P4;
  red[(wv * 5 + 4) * 64 + lane] = P5;
  __syncthreads();
  for (int idx = threadIdx.x; idx < 320; idx += 256) {
    float s = (red[idx] + red[320 + idx]) + (red[640 + idx] + red[960 + idx]);
    stats[(size_t)blockIdx.x * 320 + idx] = s;   // contiguous per block
  }
}

// Kernel 3: reduce partials -> scale/shift per column.
//   sum_h  = P1 - 16*P4;  sum_h2 = P2 - 2*P3 + 16*P5
__global__ __launch_bounds__(256) void stats_kernel(
    const float* __restrict__ stats, const float* __restrict__ gamma,
    const float* __restrict__ beta, float* __restrict__ ss) {
  const int d = blockIdx.x, t = threadIdx.x;
  float a[5];
#pragma unroll
  for (int p = 0; p < 5; ++p) {
    float s = 0.f;
    for (int k = t; k < NBLKB; k += 256) s += stats[(size_t)k * 320 + p * 64 + d];
    a[p] = s;
  }
  __shared__ float l[5][256];
#pragma unroll
  for (int p = 0; p < 5; ++p) l[p][t] = a[p];
  __syncthreads();
  for (int s = 128; s > 0; s >>= 1) {
    if (t < s) {
#pragma unroll
      for (int p = 0; p < 5; ++p) l[p][t] += l[p][t + s];
    }
    __syncthreads();
  }
  if (t == 0) {
    float P1 = l[0][0], P2 = l[1][0], P3 = l[2][0], P4 = l[3][0], P5 = l[4][0];
    const float inv = 1.0f / (float)N_EDGES;
    float mean = (P1 - 16.f * P4) * inv;
    float eh2  = (P2 - 2.f * P3 + 16.f * P5) * inv;
    float var  = fmaxf(eh2 - mean * mean, 0.f);
    float sc   = gamma[d] * rsqrtf(var + EPS);
    ss[d]      = sc;
    ss[64 + d] = beta[d] - mean * sc;
  }
}

// Kernel 4: out = relu(out*scale + shift), in place.
__global__ __launch_bounds__(256) void finalize_kernel(
    const float* __restrict__ ss, float* out) {
  int idx = blockIdx.x * 256 + threadIdx.x;   // < 6,400,000
  int d = idx & 63;
  out[idx] = fmaxf(fmaf(out[idx], ss[d], ss[64 + d]), 0.f);
}

// ---------------------------------------------------------------------------
extern "C" void kernel_launch(void* const* d_in, const int* in_sizes, int n_in,
                              void* d_out, int out_size, void* d_ws, size_t ws_size,
                              hipStream_t stream) {
  const float* nodep = (const float*)d_in[0];
  const float* feat  = (const float*)d_in[1];
  const float* W     = (const float*)d_in[2];
  const float* gamma = (const float*)d_in[3];
  const float* beta  = (const float*)d_in[4];
  const int*   edges = (const int*)d_in[5];

  // workspace layout (16B-aligned); total ~20.8 MB
  char* ws = (char*)d_ws;
  unsigned short* Wbf  = (unsigned short*)ws;                    //    12,288 B
  unsigned short* gtab = (unsigned short*)(ws + 12288);          // 12,800,000 B
  float* stats = (float*)(ws + 12288 + 12800000);                //  8,000,000 B
  float* ss    = (float*)(ws + 12288 + 12800000 + 8000000);      //       512 B
  float* outp  = (float*)d_out;

  prepw_kernel<<<24, 256, 0, stream>>>(W, Wbf);
  gtable_kernel<<<1563, 256, 0, stream>>>(feat, nodep, Wbf, gtab);
  gather_kernel<<<NBLKB, 256, 0, stream>>>(nodep, W, gamma, edges, gtab,
                                           outp, stats);
  stats_kernel<<<64, 256, 0, stream>>>(stats, gamma, beta, ss);
  finalize_kernel<<<25000, 256, 0, stream>>>(ss, outp);
}